// Round 5
// baseline (715.227 us; speedup 1.0000x reference)
//
#include <hip/hip_runtime.h>
#include <math.h>

#define NN 20000
#define H 256
#define R 64
#define EE 320000
#define LN_EPS 1e-5f
#define NB 79   // ceil(NN/256)

using short8  = __attribute__((ext_vector_type(8))) short;
using ushort8 = __attribute__((ext_vector_type(8))) unsigned short;
using f32x4   = __attribute__((ext_vector_type(4))) float;

typedef __attribute__((address_space(3))) unsigned int lds_uint;
typedef const __attribute__((address_space(1))) unsigned int glb_uint;

// fast silu: full-precision f32 div costs ~12 VALU ops without fast-math;
// v_rcp_f32 is 1 op at ~2^-22 rel err (dks values are O(1), fine).
__device__ __forceinline__ float silu_f(float x) {
    return x * __builtin_amdgcn_rcpf(1.0f + __expf(-x));
}

// round-to-nearest-even fp32 -> bf16 (as ushort)
__device__ __forceinline__ unsigned short f2bf(float f) {
    unsigned u = __float_as_uint(f);
    u += 0x7fff + ((u >> 16) & 1);
    return (unsigned short)(u >> 16);
}
__device__ __forceinline__ float bf2f(unsigned short s) {
    return __uint_as_float(((unsigned)s) << 16);
}
// f32 <-> f16 (RNE) via v_cvt
__device__ __forceinline__ unsigned short f2h(float f) {
    unsigned r;
    asm("v_cvt_f16_f32 %0, %1" : "=v"(r) : "v"(f));
    return (unsigned short)r;
}
__device__ __forceinline__ float h2f(unsigned short h) {
    float f;
    asm("v_cvt_f32_f16 %0, %1" : "=v"(f) : "v"((unsigned)h));
    return f;
}

// XOR-swizzled LDS index for [row][64] short arrays (bf16 fragments)
__device__ __forceinline__ int sw_idx(int row, int col) {
    return row * 64 + ((((col >> 3) ^ (row & 7)) << 3) | (col & 7));
}
// dks f16 [64][128]: xor col bits[5:4] by row bits[3:2]
__device__ __forceinline__ int dh_idx(int row, int col) {
    return row * 128 + (col ^ (((row >> 2) & 3) << 4));
}

// ---------------------------------------------------------------------------
// Combined prep (one launch, 242 blocks)
// ---------------------------------------------------------------------------
__global__ __launch_bounds__(256) void k_prep(
    const float* __restrict__ Wq, const float* __restrict__ Wk,
    const float* __restrict__ Wv, const float* __restrict__ Wo,
    const float* __restrict__ g,  const float* __restrict__ b,
    const float* __restrict__ bq, const float* __restrict__ bk, const float* __restrict__ bv,
    const float* __restrict__ Wdk, const float* __restrict__ Wdv,
    unsigned short* __restrict__ wqkv_p, unsigned short* __restrict__ wo_p,
    unsigned short* __restrict__ wdk_p,  unsigned short* __restrict__ wdv_p,
    float* __restrict__ bias3, int* __restrict__ hist)
{
    const int bid = blockIdx.x, t = threadIdx.x;
    if (bid < 128) {
        const int mat = bid >> 5;
        const float* W = mat == 0 ? Wq : (mat == 1 ? Wk : (mat == 2 ? Wv : Wo));
        unsigned short* out = (mat < 3) ? wqkv_p + (size_t)mat * 131072 : wo_p;
        const int fold = mat < 3;
        const int flat = (bid & 31) * 256 + t;           // [0, 8192)
        const int tile = flat >> 9;
        const int rem  = flat & 511;
        const int ks   = rem >> 6;
        const int lane = rem & 63;
        const int nl = lane & 15, quad = lane >> 4;
        const int h  = tile * 16 + nl;
        const int c0 = ks * 32 + quad * 8;
        short8 hi8, lo8;
        #pragma unroll
        for (int j = 0; j < 8; ++j) {
            float wv = W[(size_t)h * 256 + c0 + j];
            if (fold) wv *= g[c0 + j];
            const unsigned short hh = f2bf(wv);
            hi8[j] = (short)hh;
            lo8[j] = (short)f2bf(wv - bf2f(hh));
        }
        unsigned short* ob = out + ((size_t)(tile * 8 + ks)) * 1024;
        *(short8*)&ob[lane * 8] = hi8;
        *(short8*)&ob[512 + lane * 8] = lo8;
    } else if (bid < 160) {
        const int flat = (bid - 128) * 256 + t;          // [0, 8192)
        const int mat  = flat >> 12;
        const int rem  = flat & 4095;
        const int hh   = rem >> 11;
        const int r2   = rem & 2047;
        const int row  = r2 >> 4;
        const int col4 = (r2 & 15) * 4;
        const float* W = mat == 0 ? Wdk : Wdv;
        unsigned short* out = (mat == 0 ? wdk_p : wdv_p) + hh * 16384;
        const float4 w4 = *(const float4*)(W + (size_t)(hh * 128 + row) * 64 + col4);
        const unsigned short h0 = f2bf(w4.x), h1 = f2bf(w4.y), h2 = f2bf(w4.z), h3 = f2bf(w4.w);
        ushort4 hi4 = {h0, h1, h2, h3};
        ushort4 lo4 = {f2bf(w4.x - bf2f(h0)), f2bf(w4.y - bf2f(h1)),
                       f2bf(w4.z - bf2f(h2)), f2bf(w4.w - bf2f(h3))};
        const int di = sw_idx(row, col4);
        *(ushort4*)&out[di] = hi4;
        *(ushort4*)&out[8192 + di] = lo4;
    } else if (bid < 163) {
        const int mat = bid - 160, h = t;
        const float* W  = mat == 0 ? Wq : (mat == 1 ? Wk : Wv);
        const float* bb = mat == 0 ? bq : (mat == 1 ? bk : bv);
        float s = 0.f;
        const float* wr = W + (size_t)h * 256;
        for (int c = 0; c < 256; c += 4) {
            const float4 w4 = *(const float4*)(wr + c);
            const float4 b4 = *(const float4*)(b + c);
            s += w4.x * b4.x + w4.y * b4.y + w4.z * b4.z + w4.w * b4.w;
        }
        bias3[mat * 256 + h] = bb[h] + s;
    } else {
        const int i = (bid - 163) * 256 + t;
        if (i < NN) hist[i] = 0;
    }
}

// ---------------------------------------------------------------------------
// K1: LayerNorm + QKV via split-bf16 MFMA. 32 nodes per 64-thread wave:
// two A-fragment sets share each B-fragment load -> weight L2/L3 traffic
// halved (was 768KB streamed per 16 nodes = ~960 MB aggregate).
// ---------------------------------------------------------------------------
__global__ __launch_bounds__(64, 2) void k_ln_qkv(
    const float* __restrict__ x,
    const unsigned short* __restrict__ wqkv_p, const float* __restrict__ bias3,
    float* __restrict__ q, float* __restrict__ k, float* __restrict__ v)
{
    const int t = threadIdx.x;
    const int lane = t & 63;
    const int nl = lane & 15, quad = lane >> 4;
    const int nbase = blockIdx.x * 32;

    short8 a_hi[2][8], a_lo[2][8];
    #pragma unroll
    for (int s = 0; s < 2; ++s) {
        const int node = nbase + s * 16 + nl;
        const bool nv = node < NN;
        float xv[64];
        float sum = 0.f, sq = 0.f;
        const float* xp = x + (size_t)node * H + quad * 8;
        #pragma unroll
        for (int ks = 0; ks < 8; ++ks) {
            float4 x0 = {0.f,0.f,0.f,0.f}, x1 = {0.f,0.f,0.f,0.f};
            if (nv) {
                x0 = *(const float4*)(xp + ks * 32);
                x1 = *(const float4*)(xp + ks * 32 + 4);
            }
            xv[ks*8+0]=x0.x; xv[ks*8+1]=x0.y; xv[ks*8+2]=x0.z; xv[ks*8+3]=x0.w;
            xv[ks*8+4]=x1.x; xv[ks*8+5]=x1.y; xv[ks*8+6]=x1.z; xv[ks*8+7]=x1.w;
            sum += x0.x+x0.y+x0.z+x0.w + x1.x+x1.y+x1.z+x1.w;
            sq  += x0.x*x0.x+x0.y*x0.y+x0.z*x0.z+x0.w*x0.w
                 + x1.x*x1.x+x1.y*x1.y+x1.z*x1.z+x1.w*x1.w;
        }
        sum += __shfl_xor(sum, 16); sum += __shfl_xor(sum, 32);
        sq  += __shfl_xor(sq, 16);  sq  += __shfl_xor(sq, 32);
        const float mu  = sum * (1.0f / H);
        const float var = sq * (1.0f / H) - mu * mu;
        const float rs  = rsqrtf(var + LN_EPS);
        #pragma unroll
        for (int ks = 0; ks < 8; ++ks) {
            #pragma unroll
            for (int j = 0; j < 8; ++j) {
                const float z = (xv[ks*8+j] - mu) * rs;
                const unsigned short hh = f2bf(z);
                a_hi[s][ks][j] = (short)hh;
                a_lo[s][ks][j] = (short)f2bf(z - bf2f(hh));
            }
        }
    }

    for (int mat = 0; mat < 3; ++mat) {
        float* outp = mat == 0 ? q : (mat == 1 ? k : v);
        const float* bp = bias3 + mat * 256;
        const unsigned short* wb = wqkv_p + (size_t)mat * 131072 + lane * 8;
        for (int tile = 0; tile < 16; ++tile) {
            const unsigned short* gb = wb + (size_t)tile * 8192;
            const float bbv = bp[tile * 16 + nl];
            f32x4 acc0 = {bbv, bbv, bbv, bbv};
            f32x4 acc1 = {bbv, bbv, bbv, bbv};
            #pragma unroll
            for (int ks = 0; ks < 8; ++ks) {
                const short8 b_hi = *(const short8*)(gb + ks * 1024);
                const short8 b_lo = *(const short8*)(gb + ks * 1024 + 512);
                acc0 = __builtin_amdgcn_mfma_f32_16x16x32_bf16(a_hi[0][ks], b_hi, acc0, 0, 0, 0);
                acc0 = __builtin_amdgcn_mfma_f32_16x16x32_bf16(a_lo[0][ks], b_hi, acc0, 0, 0, 0);
                acc0 = __builtin_amdgcn_mfma_f32_16x16x32_bf16(a_hi[0][ks], b_lo, acc0, 0, 0, 0);
                acc1 = __builtin_amdgcn_mfma_f32_16x16x32_bf16(a_hi[1][ks], b_hi, acc1, 0, 0, 0);
                acc1 = __builtin_amdgcn_mfma_f32_16x16x32_bf16(a_lo[1][ks], b_hi, acc1, 0, 0, 0);
                acc1 = __builtin_amdgcn_mfma_f32_16x16x32_bf16(a_hi[1][ks], b_lo, acc1, 0, 0, 0);
            }
            #pragma unroll
            for (int r = 0; r < 4; ++r) {
                const int on0 = nbase + quad * 4 + r;
                const int on1 = nbase + 16 + quad * 4 + r;
                if (on0 < NN) outp[(size_t)on0 * H + tile * 16 + nl] = acc0[r];
                if (on1 < NN) outp[(size_t)on1 * H + tile * 16 + nl] = acc1[r];
            }
        }
    }
}

// ---------------------------------------------------------------------------
// Counting sort of edges by dst: hist -> scan -> scatter(perm)
// ---------------------------------------------------------------------------
__global__ __launch_bounds__(256) void k_hist(const int* __restrict__ ei, int* __restrict__ hist) {
    int e = blockIdx.x * 256 + threadIdx.x;
    if (e < EE) atomicAdd(&hist[ei[EE + e]], 1);
}

__global__ __launch_bounds__(256) void k_scan1(const int* __restrict__ hist,
                                               int* __restrict__ cursor, int* __restrict__ bsum) {
    const int t = threadIdx.x, i = blockIdx.x * 256 + t;
    const int lane = t & 63, w = t >> 6;
    const int v = (i < NN) ? hist[i] : 0;
    int incl = v;
    #pragma unroll
    for (int off = 1; off < 64; off <<= 1) {
        int u = __shfl_up(incl, off);
        if (lane >= off) incl += u;
    }
    __shared__ int ws[4];
    if (lane == 63) ws[w] = incl;
    __syncthreads();
    int base = 0;
    #pragma unroll
    for (int j = 0; j < 4; ++j) if (j < w) base += ws[j];
    if (i < NN) cursor[i] = base + incl - v;
    if (t == 255) bsum[blockIdx.x] = base + incl;
}

__global__ __launch_bounds__(128) void k_scan2(int* __restrict__ bsum) {
    __shared__ int buf[128];
    const int t = threadIdx.x;
    const int v = (t < NB) ? bsum[t] : 0;
    buf[t] = v;
    __syncthreads();
    #pragma unroll
    for (int off = 1; off < 128; off <<= 1) {
        int add = (t >= off) ? buf[t - off] : 0;
        __syncthreads();
        buf[t] += add;
        __syncthreads();
    }
    if (t < NB) bsum[t] = buf[t] - v;
}

// scan3 folded in: final position = local prefix (cursor) + block base (bsum)
__global__ __launch_bounds__(256) void k_scatter(const int* __restrict__ ei,
                                                 int* __restrict__ cursor,
                                                 const int* __restrict__ bsum,
                                                 int* __restrict__ perm) {
    int e = blockIdx.x * 256 + threadIdx.x;
    if (e < EE) {
        int d = ei[EE + e];
        int pos = atomicAdd(&cursor[d], 1) + bsum[d >> 8];
        perm[pos] = e;
    }
}

// ---------------------------------------------------------------------------
// K2: sorted-edge kernel + XCD-aware chunk swizzle.
// Round-11: WRITE_SIZE invariance across all variants => it's proportional
// to atomic-op count (device-scope fp32 atomicAdd = uncached fabric RMW on
// non-coherent-XCD gfx950: ~16B read + write accounted per dword op; 15.4M
// ops explains both the 230MB WRITE and ~240MB of FETCH excess). Fix: pass B
// restructured as a column-walk -- thread t owns col (t&127) of the hh half
// and walks 32 sorted edges, flushing per run boundary: atomic dwords/block
// 3072 -> ~1536.
// ---------------------------------------------------------------------------
__global__ __launch_bounds__(256, 2) void k_edge(
    const float* __restrict__ q, const float* __restrict__ k, const float* __restrict__ v,
    const int* __restrict__ ei, const float* __restrict__ ew, const float* __restrict__ ea,
    const unsigned short* __restrict__ wdk_p, const float* __restrict__ bdk,
    const unsigned short* __restrict__ wdv_p, const float* __restrict__ bdv,
    const int* __restrict__ perm,
    float* __restrict__ agg)
{
    __shared__ __align__(16) unsigned short w_region[2 * 128 * 64];  // 32 KB hi|lo
    __shared__ __align__(16) unsigned short dks_h[64 * 128];         // 16 KB f16 silu(dk/dv)
    __shared__ float attn_s[64];
    __shared__ int src_s[64], dst_s[64];

    const unsigned short* w_hi_s = w_region;
    const unsigned short* w_lo_s = w_region + 128 * 64;

    const int t    = threadIdx.x;
    const int bi   = blockIdx.x;
    const int eb   = ((bi & 7) * 625 + (bi >> 3)) * 64;   // XCD-contiguous chunks
    const int lane = t & 63, wave = t >> 6;
    const int nl   = lane & 15, quad = lane >> 4;
    const int estrip = wave * 16;
    const int tx = t & 31, ty = t >> 5;
    const int h0 = tx * 4, e0 = ty * 8;

    // stage image 0 (wdk half 0) as early as possible
    {
        const ushort8* sp = (const ushort8*)wdk_p + t;
        ushort8* dpw = (ushort8*)w_region + (t & 192);   // wave-uniform base
        #pragma unroll
        for (int c = 0; c < 8; ++c)
            __builtin_amdgcn_global_load_lds((glb_uint*)(sp + c * 256),
                                             (lds_uint*)(dpw + c * 256), 16, 0, 0);
    }

    if (t < 64) {
        const int e = perm[eb + t];
        src_s[t] = ei[e];
        dst_s[t] = ei[EE + e];
        attn_s[t] = 0.f;
    }

    // ea A-fragments straight from global, in-register hi/lo split
    short8 a_hi[2], a_lo[2];
    {
        const int e = perm[eb + estrip + nl];
        const float* ap = ea + (size_t)e * R + quad * 8;
        #pragma unroll
        for (int ks = 0; ks < 2; ++ks) {
            const f32x4 x0 = *(const f32x4*)(ap + ks * 32);
            const f32x4 x1 = *(const f32x4*)(ap + ks * 32 + 4);
            const float zz[8] = {x0[0], x0[1], x0[2], x0[3], x1[0], x1[1], x1[2], x1[3]};
            #pragma unroll
            for (int j = 0; j < 8; ++j) {
                const unsigned short hv = f2bf(zz[j]);
                a_hi[ks][j] = (short)hv;
                a_lo[ks][j] = (short)f2bf(zz[j] - bf2f(hv));
            }
        }
    }
    __syncthreads();   // image 0 landed; src/dst visible

    // images: 0=wdk.h0 1=wdk.h1 2=wdv.h0 3=wdv.h1
    for (int img = 0; img < 4; ++img) {
        const int hh = img & 1;

        if (img == 2 && t < 64) {
            const int e = perm[eb + t];
            const float rr = ew[e];
            const float cut = (rr < 5.0f) ? 0.5f * (__cosf(rr * 0.6283185307f) + 1.0f) : 0.0f;
            attn_s[t] = silu_f(attn_s[t]) * cut;
        }

        const float* bias = (img < 2) ? bdk : bdv;
        f32x4 accA[8];
        #pragma unroll
        for (int tt = 0; tt < 8; ++tt) {
            const int wrow = tt * 16 + nl;
            short8 b_hi[2], b_lo[2];
            #pragma unroll
            for (int ks = 0; ks < 2; ++ks) {
                const int idx = wrow * 64 + ((((ks * 4 + quad) ^ (nl & 7)) << 3));
                b_hi[ks] = *(const short8*)&w_hi_s[idx];
                b_lo[ks] = *(const short8*)&w_lo_s[idx];
            }
            const float bb = bias[hh * 128 + tt * 16 + nl];
            f32x4 acc = {bb, bb, bb, bb};
            #pragma unroll
            for (int ks = 0; ks < 2; ++ks) {
                acc = __builtin_amdgcn_mfma_f32_16x16x32_bf16(a_hi[ks], b_hi[ks], acc, 0, 0, 0);
                acc = __builtin_amdgcn_mfma_f32_16x16x32_bf16(a_lo[ks], b_hi[ks], acc, 0, 0, 0);
                acc = __builtin_amdgcn_mfma_f32_16x16x32_bf16(a_hi[ks], b_lo[ks], acc, 0, 0, 0);
            }
            accA[tt] = acc;
        }
        __syncthreads();   // all waves done reading w_region

        // issue next image's staging NOW -- lands during the edge phase below
        if (img < 3) {
            const unsigned short* nip = (img == 0) ? wdk_p + 16384
                                      : (img == 1) ? wdv_p : wdv_p + 16384;
            const ushort8* sp = (const ushort8*)nip + t;
            ushort8* dpw = (ushort8*)w_region + (t & 192);
            #pragma unroll
            for (int c = 0; c < 8; ++c)
                __builtin_amdgcn_global_load_lds((glb_uint*)(sp + c * 256),
                                                 (lds_uint*)(dpw + c * 256), 16, 0, 0);
        }

        // dks write (own wave's rows)
        #pragma unroll
        for (int tt = 0; tt < 8; ++tt)
            #pragma unroll
            for (int r = 0; r < 4; ++r)
                dks_h[dh_idx(estrip + quad * 4 + r, tt * 16 + nl)] =
                    f2h(silu_f(accA[tt][r]));

        if (img < 2) {
            // pass A: attention logits; q[dst] reused across a sorted run.
            // (reads only own wave's dks rows -> no barrier needed)
            float4 qi = {0.f, 0.f, 0.f, 0.f};
            int pd = -1;
            #pragma unroll
            for (int i = 0; i < 8; ++i) {
                const int d = dst_s[e0 + i], s = src_s[e0 + i];
                if (d != pd) {
                    qi = *(const float4*)(q + (size_t)d * H + hh * 128 + h0);
                    pd = d;
                }
                const float4 kj = *(const float4*)(k + (size_t)s * H + hh * 128 + h0);
                const ushort4 dk4 = *(const ushort4*)&dks_h[dh_idx(e0 + i, h0)];
                float part = qi.x * kj.x * h2f(dk4.x) + qi.y * kj.y * h2f(dk4.y)
                           + qi.z * kj.z * h2f(dk4.z) + qi.w * kj.w * h2f(dk4.w);
                #pragma unroll
                for (int off = 16; off; off >>= 1) part += __shfl_xor(part, off);
                if (tx == 0) attn_s[e0 + i] += part;
            }
        } else {
            // pass B column-walk: thread owns col c=(t&127); walks 32 sorted
            // edges; one atomic per (run x column). Needs all dks rows.
            __syncthreads();
            const int c    = t & 127;
            const int ebas = (t >> 7) * 32;
            float accf = 0.f;
            int cur_d = dst_s[ebas];
            #pragma unroll 8
            for (int e2 = 0; e2 < 32; ++e2) {
                const int e = ebas + e2;
                const int d = dst_s[e];
                if (d != cur_d) {
                    atomicAdd(&agg[(size_t)cur_d * H + hh * 128 + c], accf);
                    accf = 0.f; cur_d = d;
                }
                const float vv = v[(size_t)src_s[e] * H + hh * 128 + c];
                accf += vv * h2f(dks_h[dh_idx(e, c)]) * attn_s[e];
            }
            atomicAdd(&agg[(size_t)cur_d * H + hh * 128 + c], accf);
        }
        __syncthreads();   // drains vmcnt -> next image staged; phase close
    }
}

// ---------------------------------------------------------------------------
// K3: out = x + agg @ Wo'^T + bo via split-bf16 MFMA. 32 nodes / 64-thr wave
// (two A-sets share each B-fragment load: Wo traffic halved).
// ---------------------------------------------------------------------------
__global__ __launch_bounds__(64, 2) void k_out(
    const float* __restrict__ aggm, const unsigned short* __restrict__ wo_p,
    const float* __restrict__ bo, const float* __restrict__ x, float* __restrict__ out)
{
    const int t = threadIdx.x;
    const int lane = t & 63;
    const int nl = lane & 15, quad = lane >> 4;
    const int nbase = blockIdx.x * 32;

    short8 a_hi[2][8], a_lo[2][8];
    #pragma unroll
    for (int s = 0; s < 2; ++s) {
        const int node = nbase + s * 16 + nl;
        const bool nv = node < NN;
        const float* ap = aggm + (size_t)node * H + quad * 8;
        #pragma unroll
        for (int ks = 0; ks < 8; ++ks) {
            float4 x0 = {0.f,0.f,0.f,0.f}, x1 = {0.f,0.f,0.f,0.f};
            if (nv) { x0 = *(const float4*)(ap + ks * 32); x1 = *(const float4*)(ap + ks * 32 + 4); }
            const float zz[8] = {x0.x,x0.y,x0.z,x0.w,x1.x,x1.y,x1.z,x1.w};
            #pragma unroll
            for (int j = 0; j < 8; ++j) {
                const unsigned short hh = f2bf(zz[j]);
                a_hi[s][ks][j] = (short)hh;
                a_lo[s][ks][j] = (short)f2bf(zz[j] - bf2f(hh));
            }
        }
    }
    for (int tile = 0; tile < 16; ++tile) {
        const unsigned short* gb = wo_p + (size_t)tile * 8192 + lane * 8;
        const float bbv = bo[tile * 16 + nl];
        f32x4 acc0 = {bbv, bbv, bbv, bbv};
        f32x4 acc1 = {bbv, bbv, bbv, bbv};
        #pragma unroll
        for (int ks = 0; ks < 8; ++ks) {
            const short8 b_hi = *(const short8*)(gb + ks * 1024);
            const short8 b_lo = *(const short8*)(gb + ks * 1024 + 512);
            acc0 = __builtin_amdgcn_mfma_f32_16x16x32_bf16(a_hi[0][ks], b_hi, acc0, 0, 0, 0);
            acc0 = __builtin_amdgcn_mfma_f32_16x16x32_bf16(a_lo[0][ks], b_hi, acc0, 0, 0, 0);
            acc0 = __builtin_amdgcn_mfma_f32_16x16x32_bf16(a_hi[0][ks], b_lo, acc0, 0, 0, 0);
            acc1 = __builtin_amdgcn_mfma_f32_16x16x32_bf16(a_hi[1][ks], b_hi, acc1, 0, 0, 0);
            acc1 = __builtin_amdgcn_mfma_f32_16x16x32_bf16(a_lo[1][ks], b_hi, acc1, 0, 0, 0);
            acc1 = __builtin_amdgcn_mfma_f32_16x16x32_bf16(a_hi[1][ks], b_lo, acc1, 0, 0, 0);
        }
        #pragma unroll
        for (int r = 0; r < 4; ++r) {
            const int on0 = nbase + quad * 4 + r;
            const int on1 = nbase + 16 + quad * 4 + r;
            if (on0 < NN) {
                const size_t oi = (size_t)on0 * H + tile * 16 + nl;
                out[oi] = x[oi] + acc0[r];
            }
            if (on1 < NN) {
                const size_t oi = (size_t)on1 * H + tile * 16 + nl;
                out[oi] = x[oi] + acc1[r];
            }
        }
    }
}

extern "C" void kernel_launch(void* const* d_in, const int* in_sizes, int n_in,
                              void* d_out, int out_size, void* d_ws, size_t ws_size,
                              hipStream_t stream) {
    const float* x   = (const float*)d_in[0];
    const int*   ei  = (const int*)d_in[1];
    const float* ew  = (const float*)d_in[2];
    const float* ea  = (const float*)d_in[3];
    const float* g   = (const float*)d_in[4];
    const float* b   = (const float*)d_in[5];
    const float* Wq  = (const float*)d_in[6];  const float* bq  = (const float*)d_in[7];
    const float* Wk  = (const float*)d_in[8];  const float* bk  = (const float*)d_in[9];
    const float* Wv  = (const float*)d_in[10]; const float* bv  = (const float*)d_in[11];
    const float* Wo  = (const float*)d_in[12]; const float* bo  = (const float*)d_in[13];
    const float* Wdk = (const float*)d_in[14]; const float* bdk = (const float*)d_in[15];
    const float* Wdv = (const float*)d_in[16]; const float* bdv = (const float*)d_in[17];

    float* q    = (float*)d_ws;
    float* k    = q + (size_t)NN * H;
    float* v    = k + (size_t)NN * H;
    float* agg  = v + (size_t)NN * H;
    int*   hist = (int*)(agg + (size_t)NN * H);
    int*   cur  = hist + NN;
    int*   bsum = cur + NN;
    int*   perm = bsum + 128;
    unsigned short* wqkv_p = (unsigned short*)(perm + EE);
    unsigned short* wo_p   = wqkv_p + 393216;
    unsigned short* wdk_p  = wo_p + 131072;
    unsigned short* wdv_p  = wdk_p + 32768;
    float* bias3 = (float*)(wdv_p + 32768);

    hipMemsetAsync(agg, 0, (size_t)NN * H * sizeof(float), stream);
    k_prep<<<242, 256, 0, stream>>>(Wq, Wk, Wv, Wo, g, b, bq, bk, bv, Wdk, Wdv,
                                    wqkv_p, wo_p, wdk_p, wdv_p, bias3, hist);
    k_hist<<<EE / 256, 256, 0, stream>>>(ei, hist);
    k_ln_qkv<<<(NN + 31) / 32, 64, 0, stream>>>(x, wqkv_p, bias3, q, k, v);
    k_scan1<<<NB, 256, 0, stream>>>(hist, cur, bsum);
    k_scan2<<<1, 128, 0, stream>>>(bsum);
    k_scatter<<<EE / 256, 256, 0, stream>>>(ei, cur, bsum, perm);
    k_edge<<<EE / 64, 256, 0, stream>>>(q, k, v, ei, ew, ea, wdk_p, bdk, wdv_p, bdv, perm, agg);
    k_out<<<(NN + 31) / 32, 64, 0, stream>>>(agg, wo_p, bo, x, (float*)d_out);
}

// Round 6
// 630.054 us; speedup vs baseline: 1.1352x; 1.1352x over previous
//
#include <hip/hip_runtime.h>
#include <math.h>

#define NN 20000
#define H 256
#define R 64
#define EE 320000
#define LN_EPS 1e-5f
#define NB 79   // ceil(NN/256)

using short8  = __attribute__((ext_vector_type(8))) short;
using ushort8 = __attribute__((ext_vector_type(8))) unsigned short;
using f32x4   = __attribute__((ext_vector_type(4))) float;

typedef __attribute__((address_space(3))) unsigned int lds_uint;
typedef const __attribute__((address_space(1))) unsigned int glb_uint;

__device__ __forceinline__ float silu_f(float x) {
    return x * __builtin_amdgcn_rcpf(1.0f + __expf(-x));
}

// round-to-nearest-even fp32 -> bf16 (as ushort)
__device__ __forceinline__ unsigned short f2bf(float f) {
    unsigned u = __float_as_uint(f);
    u += 0x7fff + ((u >> 16) & 1);
    return (unsigned short)(u >> 16);
}
__device__ __forceinline__ float bf2f(unsigned short s) {
    return __uint_as_float(((unsigned)s) << 16);
}
// f32 <-> f16 (RNE) via v_cvt
__device__ __forceinline__ unsigned short f2h(float f) {
    unsigned r;
    asm("v_cvt_f16_f32 %0, %1" : "=v"(r) : "v"(f));
    return (unsigned short)r;
}
__device__ __forceinline__ float h2f(unsigned short h) {
    float f;
    asm("v_cvt_f32_f16 %0, %1" : "=v"(f) : "v"((unsigned)h));
    return f;
}

// XOR-swizzled LDS index for [row][64] short arrays (bf16 fragments)
__device__ __forceinline__ int sw_idx(int row, int col) {
    return row * 64 + ((((col >> 3) ^ (row & 7)) << 3) | (col & 7));
}
// dks f16 [64][256]: xor col bits[5:4] by row bits[3:2] (stays inside the
// 128-col half) -> conflict-free b16 writes, contiguous ushort4 reads.
__device__ __forceinline__ int dh_idx(int row, int col) {
    return row * 256 + (col ^ (((row >> 2) & 3) << 4));
}

// ---------------------------------------------------------------------------
// Combined prep (one launch, 242 blocks)
// ---------------------------------------------------------------------------
__global__ __launch_bounds__(256) void k_prep(
    const float* __restrict__ Wq, const float* __restrict__ Wk,
    const float* __restrict__ Wv, const float* __restrict__ Wo,
    const float* __restrict__ g,  const float* __restrict__ b,
    const float* __restrict__ bq, const float* __restrict__ bk, const float* __restrict__ bv,
    const float* __restrict__ Wdk, const float* __restrict__ Wdv,
    unsigned short* __restrict__ wqkv_p, unsigned short* __restrict__ wo_p,
    unsigned short* __restrict__ wdk_p,  unsigned short* __restrict__ wdv_p,
    float* __restrict__ bias3, int* __restrict__ hist)
{
    const int bid = blockIdx.x, t = threadIdx.x;
    if (bid < 128) {
        const int mat = bid >> 5;
        const float* W = mat == 0 ? Wq : (mat == 1 ? Wk : (mat == 2 ? Wv : Wo));
        unsigned short* out = (mat < 3) ? wqkv_p + (size_t)mat * 131072 : wo_p;
        const int fold = mat < 3;
        const int flat = (bid & 31) * 256 + t;           // [0, 8192)
        const int tile = flat >> 9;
        const int rem  = flat & 511;
        const int ks   = rem >> 6;
        const int lane = rem & 63;
        const int nl = lane & 15, quad = lane >> 4;
        const int h  = tile * 16 + nl;
        const int c0 = ks * 32 + quad * 8;
        short8 hi8, lo8;
        #pragma unroll
        for (int j = 0; j < 8; ++j) {
            float wv = W[(size_t)h * 256 + c0 + j];
            if (fold) wv *= g[c0 + j];
            const unsigned short hh = f2bf(wv);
            hi8[j] = (short)hh;
            lo8[j] = (short)f2bf(wv - bf2f(hh));
        }
        unsigned short* ob = out + ((size_t)(tile * 8 + ks)) * 1024;
        *(short8*)&ob[lane * 8] = hi8;
        *(short8*)&ob[512 + lane * 8] = lo8;
    } else if (bid < 160) {
        const int flat = (bid - 128) * 256 + t;          // [0, 8192)
        const int mat  = flat >> 12;
        const int rem  = flat & 4095;
        const int hh   = rem >> 11;
        const int r2   = rem & 2047;
        const int row  = r2 >> 4;
        const int col4 = (r2 & 15) * 4;
        const float* W = mat == 0 ? Wdk : Wdv;
        unsigned short* out = (mat == 0 ? wdk_p : wdv_p) + hh * 16384;
        const float4 w4 = *(const float4*)(W + (size_t)(hh * 128 + row) * 64 + col4);
        const unsigned short h0 = f2bf(w4.x), h1 = f2bf(w4.y), h2 = f2bf(w4.z), h3 = f2bf(w4.w);
        ushort4 hi4 = {h0, h1, h2, h3};
        ushort4 lo4 = {f2bf(w4.x - bf2f(h0)), f2bf(w4.y - bf2f(h1)),
                       f2bf(w4.z - bf2f(h2)), f2bf(w4.w - bf2f(h3))};
        const int di = sw_idx(row, col4);
        *(ushort4*)&out[di] = hi4;
        *(ushort4*)&out[8192 + di] = lo4;
    } else if (bid < 163) {
        const int mat = bid - 160, h = t;
        const float* W  = mat == 0 ? Wq : (mat == 1 ? Wk : Wv);
        const float* bb = mat == 0 ? bq : (mat == 1 ? bk : bv);
        float s = 0.f;
        const float* wr = W + (size_t)h * 256;
        for (int c = 0; c < 256; c += 4) {
            const float4 w4 = *(const float4*)(wr + c);
            const float4 b4 = *(const float4*)(b + c);
            s += w4.x * b4.x + w4.y * b4.y + w4.z * b4.z + w4.w * b4.w;
        }
        bias3[mat * 256 + h] = bb[h] + s;
    } else {
        const int i = (bid - 163) * 256 + t;
        if (i < NN) hist[i] = 0;
    }
}

// ---------------------------------------------------------------------------
// K1: LayerNorm + QKV via split-bf16 MFMA. 16 nodes per 64-thread block
// (round-1 form: 1250 single-wave blocks; the 32-node variant halved TLP
// and regressed ~35us -> reverted).
// ---------------------------------------------------------------------------
__global__ __launch_bounds__(64, 2) void k_ln_qkv(
    const float* __restrict__ x,
    const unsigned short* __restrict__ wqkv_p, const float* __restrict__ bias3,
    float* __restrict__ q, float* __restrict__ k, float* __restrict__ v)
{
    const int t = threadIdx.x;
    const int lane = t & 63;
    const int nl = lane & 15, quad = lane >> 4;
    const int nbase = blockIdx.x * 16;
    const int node = nbase + nl;
    const bool nv = node < NN;

    float xv[64];
    float sum = 0.f, sq = 0.f;
    {
        const float* xp = x + (size_t)node * H + quad * 8;
        #pragma unroll
        for (int ks = 0; ks < 8; ++ks) {
            float4 x0 = {0.f,0.f,0.f,0.f}, x1 = {0.f,0.f,0.f,0.f};
            if (nv) {
                x0 = *(const float4*)(xp + ks * 32);
                x1 = *(const float4*)(xp + ks * 32 + 4);
            }
            xv[ks*8+0]=x0.x; xv[ks*8+1]=x0.y; xv[ks*8+2]=x0.z; xv[ks*8+3]=x0.w;
            xv[ks*8+4]=x1.x; xv[ks*8+5]=x1.y; xv[ks*8+6]=x1.z; xv[ks*8+7]=x1.w;
            sum += x0.x+x0.y+x0.z+x0.w + x1.x+x1.y+x1.z+x1.w;
            sq  += x0.x*x0.x+x0.y*x0.y+x0.z*x0.z+x0.w*x0.w
                 + x1.x*x1.x+x1.y*x1.y+x1.z*x1.z+x1.w*x1.w;
        }
    }
    sum += __shfl_xor(sum, 16); sum += __shfl_xor(sum, 32);
    sq  += __shfl_xor(sq, 16);  sq  += __shfl_xor(sq, 32);
    const float mu  = sum * (1.0f / H);
    const float var = sq * (1.0f / H) - mu * mu;
    const float rs  = rsqrtf(var + LN_EPS);

    short8 a_hi[8], a_lo[8];
    #pragma unroll
    for (int ks = 0; ks < 8; ++ks) {
        #pragma unroll
        for (int j = 0; j < 8; ++j) {
            const float z = (xv[ks*8+j] - mu) * rs;
            const unsigned short hh = f2bf(z);
            a_hi[ks][j] = (short)hh;
            a_lo[ks][j] = (short)f2bf(z - bf2f(hh));
        }
    }

    for (int mat = 0; mat < 3; ++mat) {
        float* outp = mat == 0 ? q : (mat == 1 ? k : v);
        const float* bp = bias3 + mat * 256;
        const unsigned short* wb = wqkv_p + (size_t)mat * 131072 + lane * 8;
        for (int tile = 0; tile < 16; ++tile) {
            const unsigned short* gb = wb + (size_t)tile * 8192;
            const float bbv = bp[tile * 16 + nl];
            f32x4 acc = {bbv, bbv, bbv, bbv};
            #pragma unroll
            for (int ks = 0; ks < 8; ++ks) {
                const short8 b_hi = *(const short8*)(gb + ks * 1024);
                const short8 b_lo = *(const short8*)(gb + ks * 1024 + 512);
                acc = __builtin_amdgcn_mfma_f32_16x16x32_bf16(a_hi[ks], b_hi, acc, 0, 0, 0);
                acc = __builtin_amdgcn_mfma_f32_16x16x32_bf16(a_lo[ks], b_hi, acc, 0, 0, 0);
                acc = __builtin_amdgcn_mfma_f32_16x16x32_bf16(a_hi[ks], b_lo, acc, 0, 0, 0);
            }
            #pragma unroll
            for (int r = 0; r < 4; ++r) {
                const int onode = nbase + quad * 4 + r;
                if (onode < NN)
                    outp[(size_t)onode * H + tile * 16 + nl] = acc[r];
            }
        }
    }
}

// ---------------------------------------------------------------------------
// Counting sort of edges by dst: hist -> scan -> scatter(perm)
// ---------------------------------------------------------------------------
__global__ __launch_bounds__(256) void k_hist(const int* __restrict__ ei, int* __restrict__ hist) {
    int e = blockIdx.x * 256 + threadIdx.x;
    if (e < EE) atomicAdd(&hist[ei[EE + e]], 1);
}

__global__ __launch_bounds__(256) void k_scan1(const int* __restrict__ hist,
                                               int* __restrict__ cursor, int* __restrict__ bsum) {
    const int t = threadIdx.x, i = blockIdx.x * 256 + t;
    const int lane = t & 63, w = t >> 6;
    const int v = (i < NN) ? hist[i] : 0;
    int incl = v;
    #pragma unroll
    for (int off = 1; off < 64; off <<= 1) {
        int u = __shfl_up(incl, off);
        if (lane >= off) incl += u;
    }
    __shared__ int ws[4];
    if (lane == 63) ws[w] = incl;
    __syncthreads();
    int base = 0;
    #pragma unroll
    for (int j = 0; j < 4; ++j) if (j < w) base += ws[j];
    if (i < NN) cursor[i] = base + incl - v;
    if (t == 255) bsum[blockIdx.x] = base + incl;
}

__global__ __launch_bounds__(128) void k_scan2(int* __restrict__ bsum) {
    __shared__ int buf[128];
    const int t = threadIdx.x;
    const int v = (t < NB) ? bsum[t] : 0;
    buf[t] = v;
    __syncthreads();
    #pragma unroll
    for (int off = 1; off < 128; off <<= 1) {
        int add = (t >= off) ? buf[t - off] : 0;
        __syncthreads();
        buf[t] += add;
        __syncthreads();
    }
    if (t < NB) bsum[t] = buf[t] - v;
}

// scan3 folded in: final position = local prefix (cursor) + block base (bsum)
__global__ __launch_bounds__(256) void k_scatter(const int* __restrict__ ei,
                                                 int* __restrict__ cursor,
                                                 const int* __restrict__ bsum,
                                                 int* __restrict__ perm) {
    int e = blockIdx.x * 256 + threadIdx.x;
    if (e < EE) {
        int d = ei[EE + e];
        int pos = atomicAdd(&cursor[d], 1) + bsum[d >> 8];
        perm[pos] = e;
    }
}

// ---------------------------------------------------------------------------
// K2: sorted-edge kernel + XCD chunk swizzle. Round-12 restructure:
// MERGED hh halves -- per block: {stage dk.h0, MFMA, stage dk.h1, MFMA}
// filling a full [64][256] f16 dks, then ONE pass-A gather phase over full
// rows; same for dv / pass B (round-4 row-walk flush: col-walk's serial
// chain cost +23us while its 200MB atomic-write saving was time-free).
// Serialized gather phases per block: 4 -> 2; each issues 2x the independent
// loads before its single latency wait. LDS 65.3KB -> 2 blocks/CU (ledger:
// occupancy in this range is perf-neutral).
// ---------------------------------------------------------------------------
__global__ __launch_bounds__(256, 2) void k_edge(
    const float* __restrict__ q, const float* __restrict__ k, const float* __restrict__ v,
    const int* __restrict__ ei, const float* __restrict__ ew, const float* __restrict__ ea,
    const unsigned short* __restrict__ wdk_p, const float* __restrict__ bdk,
    const unsigned short* __restrict__ wdv_p, const float* __restrict__ bdv,
    const int* __restrict__ perm,
    float* __restrict__ agg)
{
    __shared__ __align__(16) unsigned short w_region[2 * 128 * 64];  // 32 KB hi|lo
    __shared__ __align__(16) unsigned short dks_h[64 * 256];         // 32 KB f16, both halves
    __shared__ float attn_s[64];
    __shared__ int src_s[64], dst_s[64];

    const unsigned short* w_hi_s = w_region;
    const unsigned short* w_lo_s = w_region + 128 * 64;

    const int t    = threadIdx.x;
    const int bi   = blockIdx.x;
    const int eb   = ((bi & 7) * 625 + (bi >> 3)) * 64;   // XCD-contiguous chunks
    const int lane = t & 63, wave = t >> 6;
    const int nl   = lane & 15, quad = lane >> 4;
    const int estrip = wave * 16;
    const int tx = t & 31, ty = t >> 5;
    const int h0 = tx * 4, e0 = ty * 8;

    // stage image 0 (wdk half 0)
    {
        const ushort8* sp = (const ushort8*)wdk_p + t;
        ushort8* dpw = (ushort8*)w_region + (t & 192);   // wave-uniform base
        #pragma unroll
        for (int c = 0; c < 8; ++c)
            __builtin_amdgcn_global_load_lds((glb_uint*)(sp + c * 256),
                                             (lds_uint*)(dpw + c * 256), 16, 0, 0);
    }

    if (t < 64) {
        const int e = perm[eb + t];
        src_s[t] = ei[e];
        dst_s[t] = ei[EE + e];
        attn_s[t] = 0.f;
    }

    // ea A-fragments straight from global, in-register hi/lo split
    short8 a_hi[2], a_lo[2];
    {
        const int e = perm[eb + estrip + nl];
        const float* ap = ea + (size_t)e * R + quad * 8;
        #pragma unroll
        for (int ks = 0; ks < 2; ++ks) {
            const f32x4 x0 = *(const f32x4*)(ap + ks * 32);
            const f32x4 x1 = *(const f32x4*)(ap + ks * 32 + 4);
            const float zz[8] = {x0[0], x0[1], x0[2], x0[3], x1[0], x1[1], x1[2], x1[3]};
            #pragma unroll
            for (int j = 0; j < 8; ++j) {
                const unsigned short hv = f2bf(zz[j]);
                a_hi[ks][j] = (short)hv;
                a_lo[ks][j] = (short)f2bf(zz[j] - bf2f(hv));
            }
        }
    }
    __syncthreads();   // image dk.h0 landed; src/dst visible

    // MFMA over the staged image -> silu -> dks columns [half*128, half*128+128)
    #define MFMA_TO_DKS(BIAS, HALF)                                                   \
    {                                                                                 \
        f32x4 accA[8];                                                                \
        _Pragma("unroll")                                                             \
        for (int tt = 0; tt < 8; ++tt) {                                              \
            const int wrow = tt * 16 + nl;                                            \
            short8 b_hi[2], b_lo[2];                                                  \
            _Pragma("unroll")                                                         \
            for (int ks = 0; ks < 2; ++ks) {                                          \
                const int idx = wrow * 64 + ((((ks * 4 + quad) ^ (nl & 7)) << 3));    \
                b_hi[ks] = *(const short8*)&w_hi_s[idx];                              \
                b_lo[ks] = *(const short8*)&w_lo_s[idx];                              \
            }                                                                         \
            const float bb = (BIAS)[(HALF) * 128 + tt * 16 + nl];                     \
            f32x4 acc = {bb, bb, bb, bb};                                             \
            _Pragma("unroll")                                                         \
            for (int ks = 0; ks < 2; ++ks) {                                          \
                acc = __builtin_amdgcn_mfma_f32_16x16x32_bf16(a_hi[ks], b_hi[ks], acc, 0, 0, 0); \
                acc = __builtin_amdgcn_mfma_f32_16x16x32_bf16(a_lo[ks], b_hi[ks], acc, 0, 0, 0); \
                acc = __builtin_amdgcn_mfma_f32_16x16x32_bf16(a_hi[ks], b_lo[ks], acc, 0, 0, 0); \
            }                                                                         \
            accA[tt] = acc;                                                           \
        }                                                                             \
        __syncthreads();  /* all waves done reading w_region */                       \
        /* next-image staging is issued by caller right after this macro */           \
        _Pragma("unroll")                                                             \
        for (int tt = 0; tt < 8; ++tt)                                                \
            _Pragma("unroll")                                                         \
            for (int r = 0; r < 4; ++r)                                               \
                dks_h[dh_idx(estrip + quad * 4 + r, (HALF) * 128 + tt * 16 + nl)] =   \
                    f2h(silu_f(accA[tt][r]));                                         \
    }

    #define STAGE(PTR)                                                                \
    {                                                                                 \
        const ushort8* sp = (const ushort8*)(PTR) + t;                                \
        ushort8* dpw = (ushort8*)w_region + (t & 192);                                \
        _Pragma("unroll")                                                             \
        for (int c = 0; c < 8; ++c)                                                   \
            __builtin_amdgcn_global_load_lds((glb_uint*)(sp + c * 256),               \
                                             (lds_uint*)(dpw + c * 256), 16, 0, 0);   \
    }

    // ---- dk half 0 ----
    {
        f32x4 accA[8];
        #pragma unroll
        for (int tt = 0; tt < 8; ++tt) {
            const int wrow = tt * 16 + nl;
            short8 b_hi[2], b_lo[2];
            #pragma unroll
            for (int ks = 0; ks < 2; ++ks) {
                const int idx = wrow * 64 + ((((ks * 4 + quad) ^ (nl & 7)) << 3));
                b_hi[ks] = *(const short8*)&w_hi_s[idx];
                b_lo[ks] = *(const short8*)&w_lo_s[idx];
            }
            const float bb = bdk[tt * 16 + nl];
            f32x4 acc = {bb, bb, bb, bb};
            #pragma unroll
            for (int ks = 0; ks < 2; ++ks) {
                acc = __builtin_amdgcn_mfma_f32_16x16x32_bf16(a_hi[ks], b_hi[ks], acc, 0, 0, 0);
                acc = __builtin_amdgcn_mfma_f32_16x16x32_bf16(a_lo[ks], b_hi[ks], acc, 0, 0, 0);
                acc = __builtin_amdgcn_mfma_f32_16x16x32_bf16(a_hi[ks], b_lo[ks], acc, 0, 0, 0);
            }
            accA[tt] = acc;
        }
        __syncthreads();           // w_region free
        STAGE(wdk_p + 16384);      // dk half 1
        #pragma unroll
        for (int tt = 0; tt < 8; ++tt)
            #pragma unroll
            for (int r = 0; r < 4; ++r)
                dks_h[dh_idx(estrip + quad * 4 + r, tt * 16 + nl)] =
                    f2h(silu_f(accA[tt][r]));
    }
    __syncthreads();               // dk.h1 landed
    // ---- dk half 1 ----
    MFMA_TO_DKS(bdk, 1);
    STAGE(wdv_p);                  // dv half 0 -- lands during pass A

    // ---- pass A: single gather phase over full 256-wide rows ----
    // (own wave's dks rows + own wave's attn rows: no barrier needed here)
    {
        float4 qi0 = {0.f,0.f,0.f,0.f}, qi1 = {0.f,0.f,0.f,0.f};
        int pd = -1;
        #pragma unroll
        for (int i = 0; i < 8; ++i) {
            const int d = dst_s[e0 + i], s = src_s[e0 + i];
            if (d != pd) {
                qi0 = *(const float4*)(q + (size_t)d * H + h0);
                qi1 = *(const float4*)(q + (size_t)d * H + 128 + h0);
                pd = d;
            }
            const float4 kj0 = *(const float4*)(k + (size_t)s * H + h0);
            const float4 kj1 = *(const float4*)(k + (size_t)s * H + 128 + h0);
            const ushort4 d40 = *(const ushort4*)&dks_h[dh_idx(e0 + i, h0)];
            const ushort4 d41 = *(const ushort4*)&dks_h[dh_idx(e0 + i, 128 + h0)];
            float part = qi0.x * kj0.x * h2f(d40.x) + qi0.y * kj0.y * h2f(d40.y)
                       + qi0.z * kj0.z * h2f(d40.z) + qi0.w * kj0.w * h2f(d40.w)
                       + qi1.x * kj1.x * h2f(d41.x) + qi1.y * kj1.y * h2f(d41.y)
                       + qi1.z * kj1.z * h2f(d41.z) + qi1.w * kj1.w * h2f(d41.w);
            #pragma unroll
            for (int off = 16; off; off >>= 1) part += __shfl_xor(part, off);
            if (tx == 0) attn_s[e0 + i] += part;
        }
    }
    __syncthreads();               // pass A complete everywhere; dv.h0 landed

    // attn finalize (wave 0); other waves proceed into MFMA (no attn use there)
    if (t < 64) {
        const int e = perm[eb + t];
        const float rr = ew[e];
        const float cut = (rr < 5.0f) ? 0.5f * (__cosf(rr * 0.6283185307f) + 1.0f) : 0.0f;
        attn_s[t] = silu_f(attn_s[t]) * cut;
    }

    // ---- dv half 0 ----
    MFMA_TO_DKS(bdv, 0);           // its internal barrier also publishes attn_s
    STAGE(wdv_p + 16384);          // dv half 1
    __syncthreads();               // dv.h1 landed
    // ---- dv half 1 ----
    MFMA_TO_DKS(bdv, 1);

    // ---- pass B: single gather phase, run-flush row-walk over 256 cols ----
    {
        float4 m0 = {0.f,0.f,0.f,0.f}, m1 = {0.f,0.f,0.f,0.f};
        int cur_d = -1;
        #pragma unroll
        for (int i = 0; i < 8; ++i) {
            const int d = dst_s[e0 + i], s = src_s[e0 + i];
            const float a = attn_s[e0 + i];
            const float4 vj0 = *(const float4*)(v + (size_t)s * H + h0);
            const float4 vj1 = *(const float4*)(v + (size_t)s * H + 128 + h0);
            const ushort4 d40 = *(const ushort4*)&dks_h[dh_idx(e0 + i, h0)];
            const ushort4 d41 = *(const ushort4*)&dks_h[dh_idx(e0 + i, 128 + h0)];
            if (d != cur_d) {
                if (cur_d >= 0) {
                    float* dp = agg + (size_t)cur_d * H;
                    atomicAdd(dp + h0 + 0, m0.x); atomicAdd(dp + h0 + 1, m0.y);
                    atomicAdd(dp + h0 + 2, m0.z); atomicAdd(dp + h0 + 3, m0.w);
                    atomicAdd(dp + 128 + h0 + 0, m1.x); atomicAdd(dp + 128 + h0 + 1, m1.y);
                    atomicAdd(dp + 128 + h0 + 2, m1.z); atomicAdd(dp + 128 + h0 + 3, m1.w);
                }
                m0.x = vj0.x * h2f(d40.x) * a; m0.y = vj0.y * h2f(d40.y) * a;
                m0.z = vj0.z * h2f(d40.z) * a; m0.w = vj0.w * h2f(d40.w) * a;
                m1.x = vj1.x * h2f(d41.x) * a; m1.y = vj1.y * h2f(d41.y) * a;
                m1.z = vj1.z * h2f(d41.z) * a; m1.w = vj1.w * h2f(d41.w) * a;
                cur_d = d;
            } else {
                m0.x += vj0.x * h2f(d40.x) * a; m0.y += vj0.y * h2f(d40.y) * a;
                m0.z += vj0.z * h2f(d40.z) * a; m0.w += vj0.w * h2f(d40.w) * a;
                m1.x += vj1.x * h2f(d41.x) * a; m1.y += vj1.y * h2f(d41.y) * a;
                m1.z += vj1.z * h2f(d41.z) * a; m1.w += vj1.w * h2f(d41.w) * a;
            }
        }
        {
            float* dp = agg + (size_t)cur_d * H;
            atomicAdd(dp + h0 + 0, m0.x); atomicAdd(dp + h0 + 1, m0.y);
            atomicAdd(dp + h0 + 2, m0.z); atomicAdd(dp + h0 + 3, m0.w);
            atomicAdd(dp + 128 + h0 + 0, m1.x); atomicAdd(dp + 128 + h0 + 1, m1.y);
            atomicAdd(dp + 128 + h0 + 2, m1.z); atomicAdd(dp + 128 + h0 + 3, m1.w);
        }
    }
    #undef MFMA_TO_DKS
    #undef STAGE
}

// ---------------------------------------------------------------------------
// K3: out = x + agg @ Wo'^T + bo via split-bf16 MFMA. 16 nodes / 64-thr block
// (round-1 form, reverted).
// ---------------------------------------------------------------------------
__global__ __launch_bounds__(64, 2) void k_out(
    const float* __restrict__ aggm, const unsigned short* __restrict__ wo_p,
    const float* __restrict__ bo, const float* __restrict__ x, float* __restrict__ out)
{
    const int t = threadIdx.x;
    const int lane = t & 63;
    const int nl = lane & 15, quad = lane >> 4;
    const int nbase = blockIdx.x * 16;
    const int node = nbase + nl;
    const bool nv = node < NN;

    short8 a_hi[8], a_lo[8];
    {
        const float* ap = aggm + (size_t)node * H + quad * 8;
        #pragma unroll
        for (int ks = 0; ks < 8; ++ks) {
            float4 x0 = {0.f,0.f,0.f,0.f}, x1 = {0.f,0.f,0.f,0.f};
            if (nv) { x0 = *(const float4*)(ap + ks * 32); x1 = *(const float4*)(ap + ks * 32 + 4); }
            const float zz[8] = {x0.x,x0.y,x0.z,x0.w,x1.x,x1.y,x1.z,x1.w};
            #pragma unroll
            for (int j = 0; j < 8; ++j) {
                const unsigned short hh = f2bf(zz[j]);
                a_hi[ks][j] = (short)hh;
                a_lo[ks][j] = (short)f2bf(zz[j] - bf2f(hh));
            }
        }
    }
    for (int tile = 0; tile < 16; ++tile) {
        const unsigned short* gb = wo_p + (size_t)tile * 8192 + lane * 8;
        const float bbv = bo[tile * 16 + nl];
        f32x4 acc = {bbv, bbv, bbv, bbv};
        #pragma unroll
        for (int ks = 0; ks < 8; ++ks) {
            const short8 b_hi = *(const short8*)(gb + ks * 1024);
            const short8 b_lo = *(const short8*)(gb + ks * 1024 + 512);
            acc = __builtin_amdgcn_mfma_f32_16x16x32_bf16(a_hi[ks], b_hi, acc, 0, 0, 0);
            acc = __builtin_amdgcn_mfma_f32_16x16x32_bf16(a_lo[ks], b_hi, acc, 0, 0, 0);
            acc = __builtin_amdgcn_mfma_f32_16x16x32_bf16(a_hi[ks], b_lo, acc, 0, 0, 0);
        }
        #pragma unroll
        for (int r = 0; r < 4; ++r) {
            const int onode = nbase + quad * 4 + r;
            if (onode < NN) {
                const size_t oi = (size_t)onode * H + tile * 16 + nl;
                out[oi] = x[oi] + acc[r];
            }
        }
    }
}

extern "C" void kernel_launch(void* const* d_in, const int* in_sizes, int n_in,
                              void* d_out, int out_size, void* d_ws, size_t ws_size,
                              hipStream_t stream) {
    const float* x   = (const float*)d_in[0];
    const int*   ei  = (const int*)d_in[1];
    const float* ew  = (const float*)d_in[2];
    const float* ea  = (const float*)d_in[3];
    const float* g   = (const float*)d_in[4];
    const float* b   = (const float*)d_in[5];
    const float* Wq  = (const float*)d_in[6];  const float* bq  = (const float*)d_in[7];
    const float* Wk  = (const float*)d_in[8];  const float* bk  = (const float*)d_in[9];
    const float* Wv  = (const float*)d_in[10]; const float* bv  = (const float*)d_in[11];
    const float* Wo  = (const float*)d_in[12]; const float* bo  = (const float*)d_in[13];
    const float* Wdk = (const float*)d_in[14]; const float* bdk = (const float*)d_in[15];
    const float* Wdv = (const float*)d_in[16]; const float* bdv = (const float*)d_in[17];

    float* q    = (float*)d_ws;
    float* k    = q + (size_t)NN * H;
    float* v    = k + (size_t)NN * H;
    float* agg  = v + (size_t)NN * H;
    int*   hist = (int*)(agg + (size_t)NN * H);
    int*   cur  = hist + NN;
    int*   bsum = cur + NN;
    int*   perm = bsum + 128;
    unsigned short* wqkv_p = (unsigned short*)(perm + EE);
    unsigned short* wo_p   = wqkv_p + 393216;
    unsigned short* wdk_p  = wo_p + 131072;
    unsigned short* wdv_p  = wdk_p + 32768;
    float* bias3 = (float*)(wdv_p + 32768);

    hipMemsetAsync(agg, 0, (size_t)NN * H * sizeof(float), stream);
    k_prep<<<242, 256, 0, stream>>>(Wq, Wk, Wv, Wo, g, b, bq, bk, bv, Wdk, Wdv,
                                    wqkv_p, wo_p, wdk_p, wdv_p, bias3, hist);
    k_hist<<<EE / 256, 256, 0, stream>>>(ei, hist);
    k_ln_qkv<<<(NN + 15) / 16, 64, 0, stream>>>(x, wqkv_p, bias3, q, k, v);
    k_scan1<<<NB, 256, 0, stream>>>(hist, cur, bsum);
    k_scan2<<<1, 128, 0, stream>>>(bsum);
    k_scatter<<<EE / 256, 256, 0, stream>>>(ei, cur, bsum, perm);
    k_edge<<<EE / 64, 256, 0, stream>>>(q, k, v, ei, ew, ea, wdk_p, bdk, wdv_p, bdv, perm, agg);
    k_out<<<(NN + 15) / 16, 64, 0, stream>>>(agg, wo_p, bo, x, (float*)d_out);
}